// Round 10
// baseline (397.403 us; speedup 1.0000x reference)
//
#include <hip/hip_runtime.h>
#include <hip/hip_bf16.h>

// BLSTM: B=1024, T=512, V=128, H=128, HH=64, gates=256/dir.
// R10: 2 independent barrier domains per CU at CONSTANT chip-wide VALU/trans.
// Block = 256 thr (4 waves), MB=4 real rows, grid 512 -> 2 blocks/CU.
// Wave w owns j in [16w,16w+16) with 4 gate-major N-tiles (i,f,g,o):
//  - every C row 0..3 is real (row=quad): exactly ONE sigma-chain per lane,
//    chip-wide transcendentals unchanged vs R9 (R6/R8 doubled them - fatal).
//  - gate transpose via per-wave LDS scratch (4 masked b128 stores by quad0 +
//    1 b128 read, same-wave in-order DS => NO barrier) - replaces R9's
//    DPP+bpermute+cndmask soup.
//  - tab gather: ONE float4 (i,f,g,o) per lane, added post-exchange; MFMA
//    accumulates from zero.
// Pure bf16 recurrence (R9-validated, absmax 9.8e-4 vs 4.24e-3 threshold).

#define T_STEPS 512
#define BATCH   1024
#define VOCAB   128
#define HID     128
#define HH      64
#define NG      256
#define MB      4      // real batch rows per block

typedef __attribute__((ext_vector_type(8))) short bf16x8;
typedef __attribute__((ext_vector_type(4))) float f32x4;
typedef unsigned int  u32;
typedef unsigned short u16;

__device__ __forceinline__ float sigmoid_f(float x) {
    return 1.0f / (1.0f + __expf(-x));
}
__device__ __forceinline__ float tanh_f(float x) {
    return 1.0f - 2.0f / (__expf(2.0f * x) + 1.0f);
}
__device__ __forceinline__ u16 f2bf_rne(float f) {
    u32 u = __builtin_bit_cast(u32, f);
    u += 0x7FFFu + ((u >> 16) & 1u);
    return (u16)(u >> 16);
}

// ---------------- Kernel 1: input-projection table, gate-major float4 ------
// tab4[(d*128+v)*64 + j] = { proj_i, proj_f, proj_g, proj_o } for hidden j
__global__ __launch_bounds__(256) void build_tab_kernel(
    const float* __restrict__ emb,
    const float* __restrict__ W_ih_f,
    const float* __restrict__ W_ih_b,
    float* __restrict__ tab4)
{
    int v = blockIdx.x, d = blockIdx.y, tid = threadIdx.x;
    int j = tid >> 2, tau = tid & 3;
    int g = tau * 64 + j;                 // original gate row
    const float* W = d ? W_ih_b : W_ih_f;
    const float4* e4 = (const float4*)(emb + v * HID);
    const float4* w4 = (const float4*)(W + g * HID);
    float acc = 0.0f;
#pragma unroll
    for (int k = 0; k < HID / 4; ++k) {
        float4 e = e4[k]; float4 w = w4[k];
        acc += e.x * w.x + e.y * w.y + e.z * w.z + e.w * w.w;
    }
    tab4[(((d * VOCAB) + v) * 64 + j) * 4 + tau] = acc;
}

// ---------------- Kernel 1b: convert W_hh to bf16 (orig order) ------------
__global__ __launch_bounds__(64) void conv_whh_kernel(
    const float* __restrict__ W_hh_f,
    const float* __restrict__ W_hh_b,
    u16* __restrict__ whh_bf)
{
    int g = blockIdx.x, d = blockIdx.y, k = threadIdx.x;
    const float* W = d ? W_hh_b : W_hh_f;
    whh_bf[(d * NG + g) * HH + k] = f2bf_rne(W[g * HH + k]);
}

// ---------------- Kernel 2: MFMA recurrence ----------------
// grid (256,2), block 256 (4 waves), 2 blocks/CU (independent barriers).
__global__ __launch_bounds__(256, 2) void lstm_rec_kernel(
    const int*  __restrict__ x,        // [1024][512]
    const u16*  __restrict__ whh_bf,   // [2][256][64] bf16 bits (orig order)
    const float* __restrict__ tab4,    // [2][128][64] float4 (i,f,g,o)
    float* __restrict__ hfin)          // [2][1024][64]
{
    __shared__ u32    xs2[T_STEPS][MB];   // v<<6 (tab4 row index), 8 KB
    __shared__ u16    hbuf[2][1024];      // [pingpong][A-frag-order elem], 4 KB
    __shared__ float4 gsc[4 * 64];        // per-wave gate-transpose scratch, 4 KB

    const int tid  = threadIdx.x;
    const int lane = tid & 63;
    const int wave = tid >> 6;           // 0..3
    const int quad = lane >> 4;          // 0..3  == my batch row
    const int m    = lane & 15;
    const int dir    = blockIdx.y;
    const int b_base = blockIdx.x * MB;

    // stage x, pre-scaled to tab4 row index (v*64)
    for (int i = tid; i < MB * T_STEPS; i += 256) {
        int bl = i >> 9, t = i & (T_STEPS - 1);
        xs2[t][bl] = ((u32)x[(b_base + bl) * T_STEPS + t]) << 6;
    }
    // zero both h buffers (M-rows 4..15 stay zero forever)
    for (int i = tid; i < 1024; i += 256) ((u32*)hbuf)[i] = 0;

    // persistent B-fragments: tile tau = gate tau, col n = j = 16*wave + m
    const u16* WB = whh_bf + dir * NG * HH;
    bf16x8 Bh[4][2];
#pragma unroll
    for (int tau = 0; tau < 4; ++tau) {
        int grow = tau * 64 + wave * 16 + m;
#pragma unroll
        for (int kc = 0; kc < 2; ++kc)
            Bh[tau][kc] = *(const bf16x8*)(WB + grow * HH + kc * 32 + quad * 8);
    }

    const float4* tabD = (const float4*)tab4 + dir * VOCAB * 64;
    const int j     = wave * 16 + m;       // my hidden unit
    // h write slot for (row=quad, k=j) in A-frag-order layout
    const int woff  = (j >> 5) * 512 + ((j >> 3) & 3) * 128 + quad * 8 + (j & 7);
    const int aoff  = lane * 8;            // u16 units
    const int gbase = wave * 64;           // float4 units

    float cc = 0.f, hcur = 0.f;
    float4 Icur, Jnxt;

    __syncthreads();   // xs2 + hbuf init visible

    {   // prefetch step 0: tab for MY row (=quad), MY j
        int t0 = dir ? (T_STEPS - 1) : 0;
        Icur = tabD[xs2[t0][quad] + j];
    }

    auto step = [&](const u16* rh, u16* wh, float4& cur, float4& nxt, int s) {
        bf16x8 Ah0 = *(const bf16x8*)(rh + aoff);
        bf16x8 Ah1 = *(const bf16x8*)(rh + 512 + aoff);

        // prefetch next step's tab (one dwordx4; overlaps MFMA + phase B)
        {
            int sn = (s + 1 < T_STEPS) ? s + 1 : s;
            int tn = dir ? (T_STEPS - 1 - sn) : sn;
            nxt = tabD[xs2[tn][quad] + j];
        }

        // gate GEMM from zero: 8 independent MFMAs (depth 2 per acc)
        f32x4 a0 = {0.f, 0.f, 0.f, 0.f};
        f32x4 a1 = {0.f, 0.f, 0.f, 0.f};
        f32x4 a2 = {0.f, 0.f, 0.f, 0.f};
        f32x4 a3 = {0.f, 0.f, 0.f, 0.f};
        a0 = __builtin_amdgcn_mfma_f32_16x16x32_bf16(Ah0, Bh[0][0], a0, 0, 0, 0);
        a1 = __builtin_amdgcn_mfma_f32_16x16x32_bf16(Ah0, Bh[1][0], a1, 0, 0, 0);
        a2 = __builtin_amdgcn_mfma_f32_16x16x32_bf16(Ah0, Bh[2][0], a2, 0, 0, 0);
        a3 = __builtin_amdgcn_mfma_f32_16x16x32_bf16(Ah0, Bh[3][0], a3, 0, 0, 0);
        a0 = __builtin_amdgcn_mfma_f32_16x16x32_bf16(Ah1, Bh[0][1], a0, 0, 0, 0);
        a1 = __builtin_amdgcn_mfma_f32_16x16x32_bf16(Ah1, Bh[1][1], a1, 0, 0, 0);
        a2 = __builtin_amdgcn_mfma_f32_16x16x32_bf16(Ah1, Bh[2][1], a2, 0, 0, 0);
        a3 = __builtin_amdgcn_mfma_f32_16x16x32_bf16(Ah1, Bh[3][1], a3, 0, 0, 0);

        // gate transpose via per-wave LDS scratch. quad0 regs r hold C rows
        // 0..3 (the only real rows). Same-wave in-order DS: no barrier needed.
        if (quad == 0) {
#pragma unroll
            for (int r = 0; r < 4; ++r)
                gsc[gbase + r * 16 + m] = float4{a0[r], a1[r], a2[r], a3[r]};
        }
        float4 g4 = gsc[gbase + quad * 16 + m];   // (i,f,g,o) for (row=quad, j)

        float gi = g4.x + cur.x;
        float gf = g4.y + cur.y;
        float gg = g4.z + cur.z;
        float go = g4.w + cur.w;

        cc   = sigmoid_f(gf) * cc + sigmoid_f(gi) * tanh_f(gg);
        hcur = sigmoid_f(go) * tanh_f(cc);

        wh[woff] = f2bf_rne(hcur);
    };

    for (int it = 0; it < T_STEPS / 2; ++it) {
        step(hbuf[0], hbuf[1], Icur, Jnxt, 2 * it);
        __syncthreads();
        step(hbuf[1], hbuf[0], Jnxt, Icur, 2 * it + 1);
        __syncthreads();
    }

    // every thread owns exactly one (row=quad, j)
    hfin[(dir * BATCH + b_base + quad) * HH + j] = hcur;
}

// ---------------- Kernel 3: final FC ----------------
__global__ __launch_bounds__(128) void fc_kernel(
    const float* __restrict__ hfin,
    const float* __restrict__ W_fc,
    const float* __restrict__ b_fc,
    float* __restrict__ out)
{
    int b = blockIdx.x;
    int v = threadIdx.x;
    __shared__ float hid[HID];
    if (v < HH) hid[v] = hfin[(0 * BATCH + b) * HH + v];
    else        hid[v] = hfin[(1 * BATCH + b) * HH + (v - HH)];
    __syncthreads();
    const float4* w4 = (const float4*)(W_fc + v * HID);
    const float4* h4 = (const float4*)hid;
    float acc = b_fc[v];
#pragma unroll
    for (int k = 0; k < HID / 4; ++k) {
        float4 w = w4[k]; float4 h = h4[k];
        acc += w.x * h.x + w.y * h.y + w.z * h.z + w.w * h.w;
    }
    out[b * HID + v] = acc;
}

extern "C" void kernel_launch(void* const* d_in, const int* in_sizes, int n_in,
                              void* d_out, int out_size, void* d_ws, size_t ws_size,
                              hipStream_t stream) {
    const int*   x      = (const int*)d_in[0];
    // d_in[1] = lengths : unused by the reference
    const float* emb    = (const float*)d_in[2];
    const float* W_ih_f = (const float*)d_in[3];
    const float* W_hh_f = (const float*)d_in[4];
    const float* W_ih_b = (const float*)d_in[5];
    const float* W_hh_b = (const float*)d_in[6];
    const float* W_fc   = (const float*)d_in[7];
    const float* b_fc   = (const float*)d_in[8];
    float* out = (float*)d_out;

    float* tab4   = (float*)d_ws;                         // 65536 f32
    u16*   whh_bf = (u16*)(tab4 + 2 * VOCAB * NG);        // 32768 u16
    float* hfin   = (float*)(whh_bf + 2 * NG * HH);       // 131072 f32

    build_tab_kernel<<<dim3(VOCAB, 2), 256, 0, stream>>>(emb, W_ih_f, W_ih_b, tab4);
    conv_whh_kernel<<<dim3(NG, 2), 64, 0, stream>>>(W_hh_f, W_hh_b, whh_bf);
    lstm_rec_kernel<<<dim3(BATCH / MB, 2), 256, 0, stream>>>(x, whh_bf, tab4, hfin);
    fc_kernel<<<dim3(BATCH), 128, 0, stream>>>(hfin, W_fc, b_fc, out);
}

// Round 11
// 394.670 us; speedup vs baseline: 1.0069x; 1.0069x over previous
//
#include <hip/hip_runtime.h>
#include <hip/hip_bf16.h>

// BLSTM: B=1024, T=512, V=128, H=128, HH=64, gates=256/dir.
// R11: R9 (best verified: 357us rec) + lgkm-only barrier. R9/R10 equivalence
// proved barrier-domain count irrelevant (2 waves/SIMD either way); the
// unmodeled wall term is the vmcnt(0) drain inside __syncthreads: the
// per-step GLOBAL tab gather must land before every barrier, every step —
// a 512x repeat of the m97 structural stall. Custom barrier waits
// lgkmcnt(0) only (h-write visibility — all the barrier semantically needs);
// the tab load's vmcnt wait moves to its use point next step (~1400 cyc
// later — fully hidden).
// Also: conv_whh folded into build_tab (one less launch).

#define T_STEPS 512
#define BATCH   1024
#define VOCAB   128
#define HID     128
#define HH      64
#define NG      256
#define MB      8      // real batch rows per block

typedef __attribute__((ext_vector_type(8))) short bf16x8;
typedef __attribute__((ext_vector_type(4))) float f32x4;
typedef unsigned int  u32;
typedef unsigned short u16;

__device__ __forceinline__ float sigmoid_f(float x) {
    return 1.0f / (1.0f + __expf(-x));
}
__device__ __forceinline__ float tanh_f(float x) {
    return 1.0f - 2.0f / (__expf(2.0f * x) + 1.0f);
}
__device__ __forceinline__ u16 f2bf_rne(float f) {
    u32 u = __builtin_bit_cast(u32, f);
    u += 0x7FFFu + ((u >> 16) & 1u);
    return (u16)(u >> 16);
}
// lane^8 within each 16-lane row == DPP row_ror:8 (VALU, no DS round trip)
__device__ __forceinline__ float dpp_xor8(float v) {
    int i = __builtin_bit_cast(int, v);
    i = __builtin_amdgcn_mov_dpp(i, 0x128, 0xF, 0xF, true);
    return __builtin_bit_cast(float, i);
}
// barrier with LDS-only drain: h produce/consume needs lgkmcnt(0)+s_barrier;
// global (tab) loads are NOT drained — their waitcnt lands at the use point.
__device__ __forceinline__ void barrier_lgkm() {
    asm volatile("s_waitcnt lgkmcnt(0)\n\ts_barrier" ::: "memory");
}

// permuted gate column c (0..255) -> original gate row g
__device__ __forceinline__ int perm_gate(int c) {
    int tile = c >> 7, rest = c & 127, w = rest >> 4, m = rest & 15;
    return (m < 8) ? (tile * 128 + w * 8 + m)
                   : (tile * 128 + 64 + w * 8 + (m - 8));
}

// ---------------- Kernel 1: tab build + W_hh bf16 convert (fused) ----------
__global__ __launch_bounds__(256) void build_tab_kernel(
    const float* __restrict__ emb,
    const float* __restrict__ W_ih_f,
    const float* __restrict__ W_ih_b,
    const float* __restrict__ W_hh_f,
    const float* __restrict__ W_hh_b,
    float* __restrict__ tab2,
    u16*   __restrict__ whh_bf)
{
    int v = blockIdx.x, d = blockIdx.y, gp = threadIdx.x;
    int tile = gp >> 7, c0 = gp & 127;
    int g = perm_gate(tile * 128 + c0);
    const float* W = d ? W_ih_b : W_ih_f;
    const float4* e4 = (const float4*)(emb + v * HID);
    const float4* w4 = (const float4*)(W + g * HID);
    float acc = 0.0f;
#pragma unroll
    for (int k = 0; k < HID / 4; ++k) {
        float4 e = e4[k]; float4 w = w4[k];
        acc += e.x * w.x + e.y * w.y + e.z * w.z + e.w * w.w;
    }
    tab2[((d * VOCAB + v) * 128 + c0) * 2 + tile] = acc;

    // fused W_hh convert: (d, v) block covers elems [(d*128+v)*128, +128)
    if (gp < 128) {
        const float* Whh = d ? W_hh_b : W_hh_f;
        int idx = v * 128 + gp;           // 0..16383 within this dir
        whh_bf[d * NG * HH + idx] = f2bf_rne(Whh[idx]);
    }
}

// ---------------- Kernel 2: MFMA recurrence ----------------
// grid (128,2), block 512 (8 waves), 1 block/CU.
__global__ __launch_bounds__(512, 2) void lstm_rec_kernel(
    const int*  __restrict__ x,        // [1024][512]
    const u16*  __restrict__ whh_bf,   // [2][256][64] bf16 bits (orig order)
    const float* __restrict__ tab2,    // [2][128][128] float2 pairs, permuted
    float* __restrict__ hfin)          // [2][1024][64]
{
    __shared__ u32 xs2[T_STEPS][MB];     // v*128 (pair index), 16 KB
    __shared__ u16 hbuf[2][1024];        // [pingpong][elem], 4 KB

    const int tid  = threadIdx.x;
    const int lane = tid & 63;
    const int wave = tid >> 6;           // 0..7
    const int quad = lane >> 4;          // 0..3
    const int m    = lane & 15;
    const int dir    = blockIdx.y;
    const int b_base = blockIdx.x * MB;

    // stage x, pre-scaled to tab2 pair index (v*128)
    for (int i = tid; i < MB * T_STEPS; i += 512) {
        int bl = i >> 9, t = i & (T_STEPS - 1);
        xs2[t][bl] = ((u32)x[(b_base + bl) * T_STEPS + t]) << 7;
    }
    // zero both h buffers (M-rows 8..15 stay zero forever)
    for (int i = tid; i < 1024; i += 512) ((u32*)hbuf)[i] = 0;

    // persistent B-fragments, permuted gate rows
    const u16* WB = whh_bf + dir * NG * HH;
    bf16x8 Bh[2][2];
#pragma unroll
    for (int tile = 0; tile < 2; ++tile) {
        int grow = perm_gate(tile * 128 + wave * 16 + m);
#pragma unroll
        for (int kc = 0; kc < 2; ++kc)
            Bh[tile][kc] = *(const bf16x8*)(WB + grow * HH + kc * 32 + quad * 8);
    }

    const float2* tabD = (const float2*)tab2 + dir * VOCAB * 128;
    const int  c0      = wave * 16 + m;          // pair-column 0..127
    const bool lohalf  = (m < 8);
    const bool hiw     = (lane >= 32);
    // the ONE real row this lane finalizes in phase B:
    const int  row     = 4 * (quad & 1) + (lohalf ? 0 : 2) + (quad >> 1);
    const int  wbase   = (wave >> 2) * 512 + (wave & 3) * 128 + (m & 7);
    const int  woff    = wbase + row * 8;
    const int  aoff    = lane * 8;               // u16 units
    const int  xrow    = (quad & 1) * 4;         // xs2 sub-row for my 4 C-rows

    float cc = 0.f, hcur = 0.f;
    float I0[4], I1[4], J0[4], J1[4];

    __syncthreads();   // xs2 + hbuf init visible (full barrier once, fine)

    {   // prefetch step 0
        int t0 = dir ? (T_STEPS - 1) : 0;
        int4 vv = *(const int4*)&xs2[t0][xrow];
        float2 p0 = tabD[(u32)vv.x + c0];
        float2 p1 = tabD[(u32)vv.y + c0];
        float2 p2 = tabD[(u32)vv.z + c0];
        float2 p3 = tabD[(u32)vv.w + c0];
        I0[0] = p0.x; I1[0] = p0.y;
        I0[1] = p1.x; I1[1] = p1.y;
        I0[2] = p2.x; I1[2] = p2.y;
        I0[3] = p3.x; I1[3] = p3.y;
    }

    auto step = [&](const u16* rh, u16* wh,
                    float (&cur0)[4], float (&cur1)[4],
                    float (&nx0)[4], float (&nx1)[4], int s) {
        bf16x8 Ah0 = *(const bf16x8*)(rh + aoff);
        bf16x8 Ah1 = *(const bf16x8*)(rh + 512 + aoff);

        // prefetch next step's tab init (global; vmcnt wait lands at use,
        // NOT at the barrier — that's the whole point of barrier_lgkm)
        {
            int sn = (s + 1 < T_STEPS) ? s + 1 : s;
            int tn = dir ? (T_STEPS - 1 - sn) : sn;
            int4 vv = *(const int4*)&xs2[tn][xrow];   // one ds_read_b128
            float2 p0 = tabD[(u32)vv.x + c0];
            float2 p1 = tabD[(u32)vv.y + c0];
            float2 p2 = tabD[(u32)vv.z + c0];
            float2 p3 = tabD[(u32)vv.w + c0];
            nx0[0] = p0.x; nx1[0] = p0.y;
            nx0[1] = p1.x; nx1[1] = p1.y;
            nx0[2] = p2.x; nx1[2] = p2.y;
            nx0[3] = p3.x; nx1[3] = p3.y;
        }

        // pure-bf16 gate GEMM: 4 MFMAs, dependent depth 2
        f32x4 acc0 = {cur0[0], cur0[1], cur0[2], cur0[3]};
        f32x4 acc1 = {cur1[0], cur1[1], cur1[2], cur1[3]};
        acc0 = __builtin_amdgcn_mfma_f32_16x16x32_bf16(Ah0, Bh[0][0], acc0, 0, 0, 0);
        acc1 = __builtin_amdgcn_mfma_f32_16x16x32_bf16(Ah0, Bh[1][0], acc1, 0, 0, 0);
        acc0 = __builtin_amdgcn_mfma_f32_16x16x32_bf16(Ah1, Bh[0][1], acc0, 0, 0, 0);
        acc1 = __builtin_amdgcn_mfma_f32_16x16x32_bf16(Ah1, Bh[1][1], acc1, 0, 0, 0);

        // xor8 exchange via DPP (VALU): complete (i,f,g,o) for my 2 C rows
        float e0 = dpp_xor8(lohalf ? acc0[2] : acc0[0]);
        float e1 = dpp_xor8(lohalf ? acc0[3] : acc0[1]);
        float e2 = dpp_xor8(lohalf ? acc1[2] : acc1[0]);
        float e3 = dpp_xor8(lohalf ? acc1[3] : acc1[1]);

        float i0 = lohalf ? acc0[0] : e0;    // row r0
        float f0 = lohalf ? e0 : acc0[2];
        float g0 = lohalf ? acc1[0] : e2;
        float o0 = lohalf ? e2 : acc1[2];
        float i1 = lohalf ? acc0[1] : e1;    // row r0+1
        float f1 = lohalf ? e1 : acc0[3];
        float g1 = lohalf ? acc1[1] : e3;
        float o1 = lohalf ? e3 : acc1[3];

        // xor32: ship row-B gates; lanes>=32 take over partner's row r0+1
        float ri = __shfl_xor(i1, 32);
        float rf = __shfl_xor(f1, 32);
        float rg = __shfl_xor(g1, 32);
        float ro = __shfl_xor(o1, 32);
        float gi = hiw ? ri : i0;
        float gf = hiw ? rf : f0;
        float gg = hiw ? rg : g0;
        float go = hiw ? ro : o0;

        cc   = sigmoid_f(gf) * cc + sigmoid_f(gi) * tanh_f(gg);
        hcur = sigmoid_f(go) * tanh_f(cc);

        wh[woff] = f2bf_rne(hcur);
    };

    for (int it = 0; it < T_STEPS / 2; ++it) {
        step(hbuf[0], hbuf[1], I0, I1, J0, J1, 2 * it);
        barrier_lgkm();
        step(hbuf[1], hbuf[0], J0, J1, I0, I1, 2 * it + 1);
        barrier_lgkm();
    }

    // every thread owns exactly one (b, j)
    {
        int j = wave * 8 + (m & 7);
        hfin[(dir * BATCH + b_base + row) * HH + j] = hcur;
    }
}

// ---------------- Kernel 3: final FC ----------------
__global__ __launch_bounds__(128) void fc_kernel(
    const float* __restrict__ hfin,
    const float* __restrict__ W_fc,
    const float* __restrict__ b_fc,
    float* __restrict__ out)
{
    int b = blockIdx.x;
    int v = threadIdx.x;
    __shared__ float hid[HID];
    if (v < HH) hid[v] = hfin[(0 * BATCH + b) * HH + v];
    else        hid[v] = hfin[(1 * BATCH + b) * HH + (v - HH)];
    __syncthreads();
    const float4* w4 = (const float4*)(W_fc + v * HID);
    const float4* h4 = (const float4*)hid;
    float acc = b_fc[v];
#pragma unroll
    for (int k = 0; k < HID / 4; ++k) {
        float4 w = w4[k]; float4 h = h4[k];
        acc += w.x * h.x + w.y * h.y + w.z * h.z + w.w * h.w;
    }
    out[b * HID + v] = acc;
}

extern "C" void kernel_launch(void* const* d_in, const int* in_sizes, int n_in,
                              void* d_out, int out_size, void* d_ws, size_t ws_size,
                              hipStream_t stream) {
    const int*   x      = (const int*)d_in[0];
    // d_in[1] = lengths : unused by the reference
    const float* emb    = (const float*)d_in[2];
    const float* W_ih_f = (const float*)d_in[3];
    const float* W_hh_f = (const float*)d_in[4];
    const float* W_ih_b = (const float*)d_in[5];
    const float* W_hh_b = (const float*)d_in[6];
    const float* W_fc   = (const float*)d_in[7];
    const float* b_fc   = (const float*)d_in[8];
    float* out = (float*)d_out;

    float* tab2   = (float*)d_ws;                         // 65536 f32 (pairs)
    u16*   whh_bf = (u16*)(tab2 + 2 * VOCAB * NG);        // 32768 u16
    float* hfin   = (float*)(whh_bf + 2 * NG * HH);       // 131072 f32

    build_tab_kernel<<<dim3(VOCAB, 2), 256, 0, stream>>>(
        emb, W_ih_f, W_ih_b, W_hh_f, W_hh_b, tab2, whh_bf);
    lstm_rec_kernel<<<dim3(BATCH / MB, 2), 512, 0, stream>>>(x, whh_bf, tab2, hfin);
    fc_kernel<<<dim3(BATCH), 128, 0, stream>>>(hfin, W_fc, b_fc, out);
}

// Round 13
// 321.310 us; speedup vs baseline: 1.2368x; 1.2283x over previous
//
#include <hip/hip_runtime.h>
#include <hip/hip_bf16.h>

// BLSTM: B=1024, T=512, V=128, H=128, HH=64, gates=256/dir.
// R13: bisect after R12's numeric failure (4 simultaneous changes, absmax
// 6e-2). This is R11 (passing, 350us rec) + EXACTLY ONE change: cheap
// transcendentals. Under plain -O3 (no fast-math) each 1.0f/x expands to the
// ~10-inst IEEE div sequence; 5 per lane per step. Replaced with
// v_rcp_f32 (<=1 ulp — invisible under bf16 h rounding) and explicit
// exp2(x*log2e). No weight prescale, no bf16 tab, no permlane (R12 suspects).
// Skeleton: MB=8, 8 waves, 1 lgkm-barrier/step, conflict-free A-frag h
// layout, DPP xor8 + bpermute xor32, one sigma-chain per lane (R9-R11).

#define T_STEPS 512
#define BATCH   1024
#define VOCAB   128
#define HID     128
#define HH      64
#define NG      256
#define MB      8      // real batch rows per block

#define L2E  1.4426950408889634f
#define L2E2 2.8853900817779268f

typedef __attribute__((ext_vector_type(8))) short bf16x8;
typedef __attribute__((ext_vector_type(4))) float f32x4;
typedef unsigned int  u32;
typedef unsigned short u16;

__device__ __forceinline__ float sigmoid_f(float x) {
    return __builtin_amdgcn_rcpf(1.0f + __builtin_amdgcn_exp2f(-x * L2E));
}
__device__ __forceinline__ float tanh_f(float x) {
    return 1.0f - 2.0f * __builtin_amdgcn_rcpf(1.0f + __builtin_amdgcn_exp2f(x * L2E2));
}
__device__ __forceinline__ u16 f2bf_rne(float f) {
    u32 u = __builtin_bit_cast(u32, f);
    u += 0x7FFFu + ((u >> 16) & 1u);
    return (u16)(u >> 16);
}
// lane^8 within each 16-lane row == DPP row_ror:8 (VALU, no DS round trip)
__device__ __forceinline__ float dpp_xor8(float v) {
    int i = __builtin_bit_cast(int, v);
    i = __builtin_amdgcn_mov_dpp(i, 0x128, 0xF, 0xF, true);
    return __builtin_bit_cast(float, i);
}
// barrier with LDS-only drain: h produce/consume needs lgkmcnt(0)+s_barrier;
// global (tab) loads are NOT drained — their waitcnt lands at the use point.
__device__ __forceinline__ void barrier_lgkm() {
    asm volatile("s_waitcnt lgkmcnt(0)\n\ts_barrier" ::: "memory");
}

// permuted gate column c (0..255) -> original gate row g
__device__ __forceinline__ int perm_gate(int c) {
    int tile = c >> 7, rest = c & 127, w = rest >> 4, m = rest & 15;
    return (m < 8) ? (tile * 128 + w * 8 + m)
                   : (tile * 128 + 64 + w * 8 + (m - 8));
}

// ---------------- Kernel 1: tab build + W_hh bf16 convert (fused) ----------
__global__ __launch_bounds__(256) void build_tab_kernel(
    const float* __restrict__ emb,
    const float* __restrict__ W_ih_f,
    const float* __restrict__ W_ih_b,
    const float* __restrict__ W_hh_f,
    const float* __restrict__ W_hh_b,
    float* __restrict__ tab2,
    u16*   __restrict__ whh_bf)
{
    int v = blockIdx.x, d = blockIdx.y, gp = threadIdx.x;
    int tile = gp >> 7, c0 = gp & 127;
    int g = perm_gate(tile * 128 + c0);
    const float* W = d ? W_ih_b : W_ih_f;
    const float4* e4 = (const float4*)(emb + v * HID);
    const float4* w4 = (const float4*)(W + g * HID);
    float acc = 0.0f;
#pragma unroll
    for (int k = 0; k < HID / 4; ++k) {
        float4 e = e4[k]; float4 w = w4[k];
        acc += e.x * w.x + e.y * w.y + e.z * w.z + e.w * w.w;
    }
    tab2[((d * VOCAB + v) * 128 + c0) * 2 + tile] = acc;

    // fused W_hh convert: (d, v) block covers elems [(d*128+v)*128, +128)
    if (gp < 128) {
        const float* Whh = d ? W_hh_b : W_hh_f;
        int idx = v * 128 + gp;           // 0..16383 within this dir
        whh_bf[d * NG * HH + idx] = f2bf_rne(Whh[idx]);
    }
}

// ---------------- Kernel 2: MFMA recurrence ----------------
// grid (128,2), block 512 (8 waves), 1 block/CU.
__global__ __launch_bounds__(512, 2) void lstm_rec_kernel(
    const int*  __restrict__ x,        // [1024][512]
    const u16*  __restrict__ whh_bf,   // [2][256][64] bf16 bits (orig order)
    const float* __restrict__ tab2,    // [2][128][128] float2 pairs, permuted
    float* __restrict__ hfin)          // [2][1024][64]
{
    __shared__ u32 xs2[T_STEPS][MB];     // v*128 (pair index), 16 KB
    __shared__ u16 hbuf[2][1024];        // [pingpong][elem], 4 KB

    const int tid  = threadIdx.x;
    const int lane = tid & 63;
    const int wave = tid >> 6;           // 0..7
    const int quad = lane >> 4;          // 0..3
    const int m    = lane & 15;
    const int dir    = blockIdx.y;
    const int b_base = blockIdx.x * MB;

    // stage x, pre-scaled to tab2 pair index (v*128)
    for (int i = tid; i < MB * T_STEPS; i += 512) {
        int bl = i >> 9, t = i & (T_STEPS - 1);
        xs2[t][bl] = ((u32)x[(b_base + bl) * T_STEPS + t]) << 7;
    }
    // zero both h buffers (M-rows 8..15 stay zero forever)
    for (int i = tid; i < 1024; i += 512) ((u32*)hbuf)[i] = 0;

    // persistent B-fragments, permuted gate rows
    const u16* WB = whh_bf + dir * NG * HH;
    bf16x8 Bh[2][2];
#pragma unroll
    for (int tile = 0; tile < 2; ++tile) {
        int grow = perm_gate(tile * 128 + wave * 16 + m);
#pragma unroll
        for (int kc = 0; kc < 2; ++kc)
            Bh[tile][kc] = *(const bf16x8*)(WB + grow * HH + kc * 32 + quad * 8);
    }

    const float2* tabD = (const float2*)tab2 + dir * VOCAB * 128;
    const int  c0      = wave * 16 + m;          // pair-column 0..127
    const bool lohalf  = (m < 8);
    const bool hiw     = (lane >= 32);
    // the ONE real row this lane finalizes in phase B:
    const int  row     = 4 * (quad & 1) + (lohalf ? 0 : 2) + (quad >> 1);
    const int  wbase   = (wave >> 2) * 512 + (wave & 3) * 128 + (m & 7);
    const int  woff    = wbase + row * 8;
    const int  aoff    = lane * 8;               // u16 units
    const int  xrow    = (quad & 1) * 4;         // xs2 sub-row for my 4 C-rows

    float cc = 0.f, hcur = 0.f;
    float I0[4], I1[4], J0[4], J1[4];

    __syncthreads();   // xs2 + hbuf init visible (full barrier once, fine)

    {   // prefetch step 0
        int t0 = dir ? (T_STEPS - 1) : 0;
        int4 vv = *(const int4*)&xs2[t0][xrow];
        float2 p0 = tabD[(u32)vv.x + c0];
        float2 p1 = tabD[(u32)vv.y + c0];
        float2 p2 = tabD[(u32)vv.z + c0];
        float2 p3 = tabD[(u32)vv.w + c0];
        I0[0] = p0.x; I1[0] = p0.y;
        I0[1] = p1.x; I1[1] = p1.y;
        I0[2] = p2.x; I1[2] = p2.y;
        I0[3] = p3.x; I1[3] = p3.y;
    }

    auto step = [&](const u16* rh, u16* wh,
                    float (&cur0)[4], float (&cur1)[4],
                    float (&nx0)[4], float (&nx1)[4], int s) {
        bf16x8 Ah0 = *(const bf16x8*)(rh + aoff);
        bf16x8 Ah1 = *(const bf16x8*)(rh + 512 + aoff);

        // prefetch next step's tab init (global; vmcnt wait lands at use,
        // NOT at the barrier — barrier_lgkm drains LDS only)
        {
            int sn = (s + 1 < T_STEPS) ? s + 1 : s;
            int tn = dir ? (T_STEPS - 1 - sn) : sn;
            int4 vv = *(const int4*)&xs2[tn][xrow];   // one ds_read_b128
            float2 p0 = tabD[(u32)vv.x + c0];
            float2 p1 = tabD[(u32)vv.y + c0];
            float2 p2 = tabD[(u32)vv.z + c0];
            float2 p3 = tabD[(u32)vv.w + c0];
            nx0[0] = p0.x; nx1[0] = p0.y;
            nx0[1] = p1.x; nx1[1] = p1.y;
            nx0[2] = p2.x; nx1[2] = p2.y;
            nx0[3] = p3.x; nx1[3] = p3.y;
        }

        // pure-bf16 gate GEMM: 4 MFMAs, dependent depth 2
        f32x4 acc0 = {cur0[0], cur0[1], cur0[2], cur0[3]};
        f32x4 acc1 = {cur1[0], cur1[1], cur1[2], cur1[3]};
        acc0 = __builtin_amdgcn_mfma_f32_16x16x32_bf16(Ah0, Bh[0][0], acc0, 0, 0, 0);
        acc1 = __builtin_amdgcn_mfma_f32_16x16x32_bf16(Ah0, Bh[1][0], acc1, 0, 0, 0);
        acc0 = __builtin_amdgcn_mfma_f32_16x16x32_bf16(Ah1, Bh[0][1], acc0, 0, 0, 0);
        acc1 = __builtin_amdgcn_mfma_f32_16x16x32_bf16(Ah1, Bh[1][1], acc1, 0, 0, 0);

        // xor8 exchange via DPP (VALU): complete (i,f,g,o) for my 2 C rows
        float e0 = dpp_xor8(lohalf ? acc0[2] : acc0[0]);
        float e1 = dpp_xor8(lohalf ? acc0[3] : acc0[1]);
        float e2 = dpp_xor8(lohalf ? acc1[2] : acc1[0]);
        float e3 = dpp_xor8(lohalf ? acc1[3] : acc1[1]);

        float i0 = lohalf ? acc0[0] : e0;    // row r0
        float f0 = lohalf ? e0 : acc0[2];
        float g0 = lohalf ? acc1[0] : e2;
        float o0 = lohalf ? e2 : acc1[2];
        float i1 = lohalf ? acc0[1] : e1;    // row r0+1
        float f1 = lohalf ? e1 : acc0[3];
        float g1 = lohalf ? acc1[1] : e3;
        float o1 = lohalf ? e3 : acc1[3];

        // xor32: ship row-B gates; lanes>=32 take over partner's row r0+1
        float ri = __shfl_xor(i1, 32);
        float rf = __shfl_xor(f1, 32);
        float rg = __shfl_xor(g1, 32);
        float ro = __shfl_xor(o1, 32);
        float gi = hiw ? ri : i0;
        float gf = hiw ? rf : f0;
        float gg = hiw ? rg : g0;
        float go = hiw ? ro : o0;

        cc   = sigmoid_f(gf) * cc + sigmoid_f(gi) * tanh_f(gg);
        hcur = sigmoid_f(go) * tanh_f(cc);

        wh[woff] = f2bf_rne(hcur);
    };

    for (int it = 0; it < T_STEPS / 2; ++it) {
        step(hbuf[0], hbuf[1], I0, I1, J0, J1, 2 * it);
        barrier_lgkm();
        step(hbuf[1], hbuf[0], J0, J1, I0, I1, 2 * it + 1);
        barrier_lgkm();
    }

    // every thread owns exactly one (b, j)
    {
        int j = wave * 8 + (m & 7);
        hfin[(dir * BATCH + b_base + row) * HH + j] = hcur;
    }
}

// ---------------- Kernel 3: final FC ----------------
__global__ __launch_bounds__(128) void fc_kernel(
    const float* __restrict__ hfin,
    const float* __restrict__ W_fc,
    const float* __restrict__ b_fc,
    float* __restrict__ out)
{
    int b = blockIdx.x;
    int v = threadIdx.x;
    __shared__ float hid[HID];
    if (v < HH) hid[v] = hfin[(0 * BATCH + b) * HH + v];
    else        hid[v] = hfin[(1 * BATCH + b) * HH + (v - HH)];
    __syncthreads();
    const float4* w4 = (const float4*)(W_fc + v * HID);
    const float4* h4 = (const float4*)hid;
    float acc = b_fc[v];
#pragma unroll
    for (int k = 0; k < HID / 4; ++k) {
        float4 w = w4[k]; float4 h = h4[k];
        acc += w.x * h.x + w.y * h.y + w.z * h.z + w.w * h.w;
    }
    out[b * HID + v] = acc;
}

extern "C" void kernel_launch(void* const* d_in, const int* in_sizes, int n_in,
                              void* d_out, int out_size, void* d_ws, size_t ws_size,
                              hipStream_t stream) {
    const int*   x      = (const int*)d_in[0];
    // d_in[1] = lengths : unused by the reference
    const float* emb    = (const float*)d_in[2];
    const float* W_ih_f = (const float*)d_in[3];
    const float* W_hh_f = (const float*)d_in[4];
    const float* W_ih_b = (const float*)d_in[5];
    const float* W_hh_b = (const float*)d_in[6];
    const float* W_fc   = (const float*)d_in[7];
    const float* b_fc   = (const float*)d_in[8];
    float* out = (float*)d_out;

    float* tab2   = (float*)d_ws;                         // 65536 f32 (pairs)
    u16*   whh_bf = (u16*)(tab2 + 2 * VOCAB * NG);        // 32768 u16
    float* hfin   = (float*)(whh_bf + 2 * NG * HH);       // 131072 f32

    build_tab_kernel<<<dim3(VOCAB, 2), 256, 0, stream>>>(
        emb, W_ih_f, W_ih_b, W_hh_f, W_hh_b, tab2, whh_bf);
    lstm_rec_kernel<<<dim3(BATCH / MB, 2), 512, 0, stream>>>(x, whh_bf, tab2, hfin);
    fc_kernel<<<dim3(BATCH), 128, 0, stream>>>(hfin, W_fc, b_fc, out);
}

// Round 15
// 320.395 us; speedup vs baseline: 1.2404x; 1.0029x over previous
//
#include <hip/hip_runtime.h>
#include <hip/hip_bf16.h>

// BLSTM: B=1024, T=512, V=128, H=128, HH=64, gates=256/dir.
// R15: R13 rec kernel VERBATIM (264us, absmax 9.766e-4) + lean fc_kernel
// (validated: R12 vs R14 identical absmax proves fc-new == fc-old output).
// permlane32_swap is ABANDONED: R12/R14 bit-identical failures (5.975e-2)
// attribute the bug to it — probe-calibrated asm("+v","+v") semantics don't
// transfer across register-allocation instances (same-value operands can be
// merged into one register, changing the swap behavior). xor32 stays
// __shfl_xor (ds_bpermute) — proven.
// Rec skeleton (R9-R13): MB=8, 8 waves, 1 lgkm-barrier/step, pure-bf16 gate
// GEMM (4 MFMAs), conflict-free A-frag h layout, DPP xor8, rcp/exp2
// transcendentals, one sigma-chain per lane.

#define T_STEPS 512
#define BATCH   1024
#define VOCAB   128
#define HID     128
#define HH      64
#define NG      256
#define MB      8      // real batch rows per block

#define L2E  1.4426950408889634f
#define L2E2 2.8853900817779268f

typedef __attribute__((ext_vector_type(8))) short bf16x8;
typedef __attribute__((ext_vector_type(4))) float f32x4;
typedef unsigned int  u32;
typedef unsigned short u16;

__device__ __forceinline__ float sigmoid_f(float x) {
    return __builtin_amdgcn_rcpf(1.0f + __builtin_amdgcn_exp2f(-x * L2E));
}
__device__ __forceinline__ float tanh_f(float x) {
    return 1.0f - 2.0f * __builtin_amdgcn_rcpf(1.0f + __builtin_amdgcn_exp2f(x * L2E2));
}
__device__ __forceinline__ u16 f2bf_rne(float f) {
    u32 u = __builtin_bit_cast(u32, f);
    u += 0x7FFFu + ((u >> 16) & 1u);
    return (u16)(u >> 16);
}
// lane^8 within each 16-lane row == DPP row_ror:8 (VALU, no DS round trip)
__device__ __forceinline__ float dpp_xor8(float v) {
    int i = __builtin_bit_cast(int, v);
    i = __builtin_amdgcn_mov_dpp(i, 0x128, 0xF, 0xF, true);
    return __builtin_bit_cast(float, i);
}
// barrier with LDS-only drain: h produce/consume needs lgkmcnt(0)+s_barrier;
// global (tab) loads are NOT drained — their waitcnt lands at the use point.
__device__ __forceinline__ void barrier_lgkm() {
    asm volatile("s_waitcnt lgkmcnt(0)\n\ts_barrier" ::: "memory");
}

// permuted gate column c (0..255) -> original gate row g
__device__ __forceinline__ int perm_gate(int c) {
    int tile = c >> 7, rest = c & 127, w = rest >> 4, m = rest & 15;
    return (m < 8) ? (tile * 128 + w * 8 + m)
                   : (tile * 128 + 64 + w * 8 + (m - 8));
}

// ---------------- Kernel 1: tab build + W_hh bf16 convert (fused) ----------
__global__ __launch_bounds__(256) void build_tab_kernel(
    const float* __restrict__ emb,
    const float* __restrict__ W_ih_f,
    const float* __restrict__ W_ih_b,
    const float* __restrict__ W_hh_f,
    const float* __restrict__ W_hh_b,
    float* __restrict__ tab2,
    u16*   __restrict__ whh_bf)
{
    int v = blockIdx.x, d = blockIdx.y, gp = threadIdx.x;
    int tile = gp >> 7, c0 = gp & 127;
    int g = perm_gate(tile * 128 + c0);
    const float* W = d ? W_ih_b : W_ih_f;
    const float4* e4 = (const float4*)(emb + v * HID);
    const float4* w4 = (const float4*)(W + g * HID);
    float acc = 0.0f;
#pragma unroll
    for (int k = 0; k < HID / 4; ++k) {
        float4 e = e4[k]; float4 w = w4[k];
        acc += e.x * w.x + e.y * w.y + e.z * w.z + e.w * w.w;
    }
    tab2[((d * VOCAB + v) * 128 + c0) * 2 + tile] = acc;

    // fused W_hh convert: (d, v) block covers elems [(d*128+v)*128, +128)
    if (gp < 128) {
        const float* Whh = d ? W_hh_b : W_hh_f;
        int idx = v * 128 + gp;           // 0..16383 within this dir
        whh_bf[d * NG * HH + idx] = f2bf_rne(Whh[idx]);
    }
}

// ---------------- Kernel 2: MFMA recurrence (R13 verbatim) ----------------
// grid (128,2), block 512 (8 waves), 1 block/CU.
__global__ __launch_bounds__(512, 2) void lstm_rec_kernel(
    const int*  __restrict__ x,        // [1024][512]
    const u16*  __restrict__ whh_bf,   // [2][256][64] bf16 bits (orig order)
    const float* __restrict__ tab2,    // [2][128][128] float2 pairs, permuted
    float* __restrict__ hfin)          // [2][1024][64]
{
    __shared__ u32 xs2[T_STEPS][MB];     // v*128 (pair index), 16 KB
    __shared__ u16 hbuf[2][1024];        // [pingpong][elem], 4 KB

    const int tid  = threadIdx.x;
    const int lane = tid & 63;
    const int wave = tid >> 6;           // 0..7
    const int quad = lane >> 4;          // 0..3
    const int m    = lane & 15;
    const int dir    = blockIdx.y;
    const int b_base = blockIdx.x * MB;

    // stage x, pre-scaled to tab2 pair index (v*128)
    for (int i = tid; i < MB * T_STEPS; i += 512) {
        int bl = i >> 9, t = i & (T_STEPS - 1);
        xs2[t][bl] = ((u32)x[(b_base + bl) * T_STEPS + t]) << 7;
    }
    // zero both h buffers (M-rows 8..15 stay zero forever)
    for (int i = tid; i < 1024; i += 512) ((u32*)hbuf)[i] = 0;

    // persistent B-fragments, permuted gate rows
    const u16* WB = whh_bf + dir * NG * HH;
    bf16x8 Bh[2][2];
#pragma unroll
    for (int tile = 0; tile < 2; ++tile) {
        int grow = perm_gate(tile * 128 + wave * 16 + m);
#pragma unroll
        for (int kc = 0; kc < 2; ++kc)
            Bh[tile][kc] = *(const bf16x8*)(WB + grow * HH + kc * 32 + quad * 8);
    }

    const float2* tabD = (const float2*)tab2 + dir * VOCAB * 128;
    const int  c0      = wave * 16 + m;          // pair-column 0..127
    const bool lohalf  = (m < 8);
    const bool hiw     = (lane >= 32);
    // the ONE real row this lane finalizes in phase B:
    const int  row     = 4 * (quad & 1) + (lohalf ? 0 : 2) + (quad >> 1);
    const int  wbase   = (wave >> 2) * 512 + (wave & 3) * 128 + (m & 7);
    const int  woff    = wbase + row * 8;
    const int  aoff    = lane * 8;               // u16 units
    const int  xrow    = (quad & 1) * 4;         // xs2 sub-row for my 4 C-rows

    float cc = 0.f, hcur = 0.f;
    float I0[4], I1[4], J0[4], J1[4];

    __syncthreads();   // xs2 + hbuf init visible (full barrier once, fine)

    {   // prefetch step 0
        int t0 = dir ? (T_STEPS - 1) : 0;
        int4 vv = *(const int4*)&xs2[t0][xrow];
        float2 p0 = tabD[(u32)vv.x + c0];
        float2 p1 = tabD[(u32)vv.y + c0];
        float2 p2 = tabD[(u32)vv.z + c0];
        float2 p3 = tabD[(u32)vv.w + c0];
        I0[0] = p0.x; I1[0] = p0.y;
        I0[1] = p1.x; I1[1] = p1.y;
        I0[2] = p2.x; I1[2] = p2.y;
        I0[3] = p3.x; I1[3] = p3.y;
    }

    auto step = [&](const u16* rh, u16* wh,
                    float (&cur0)[4], float (&cur1)[4],
                    float (&nx0)[4], float (&nx1)[4], int s) {
        bf16x8 Ah0 = *(const bf16x8*)(rh + aoff);
        bf16x8 Ah1 = *(const bf16x8*)(rh + 512 + aoff);

        // prefetch next step's tab init (global; vmcnt wait lands at use,
        // NOT at the barrier — barrier_lgkm drains LDS only)
        {
            int sn = (s + 1 < T_STEPS) ? s + 1 : s;
            int tn = dir ? (T_STEPS - 1 - sn) : sn;
            int4 vv = *(const int4*)&xs2[tn][xrow];   // one ds_read_b128
            float2 p0 = tabD[(u32)vv.x + c0];
            float2 p1 = tabD[(u32)vv.y + c0];
            float2 p2 = tabD[(u32)vv.z + c0];
            float2 p3 = tabD[(u32)vv.w + c0];
            nx0[0] = p0.x; nx1[0] = p0.y;
            nx0[1] = p1.x; nx1[1] = p1.y;
            nx0[2] = p2.x; nx1[2] = p2.y;
            nx0[3] = p3.x; nx1[3] = p3.y;
        }

        // pure-bf16 gate GEMM: 4 MFMAs, dependent depth 2
        f32x4 acc0 = {cur0[0], cur0[1], cur0[2], cur0[3]};
        f32x4 acc1 = {cur1[0], cur1[1], cur1[2], cur1[3]};
        acc0 = __builtin_amdgcn_mfma_f32_16x16x32_bf16(Ah0, Bh[0][0], acc0, 0, 0, 0);
        acc1 = __builtin_amdgcn_mfma_f32_16x16x32_bf16(Ah0, Bh[1][0], acc1, 0, 0, 0);
        acc0 = __builtin_amdgcn_mfma_f32_16x16x32_bf16(Ah1, Bh[0][1], acc0, 0, 0, 0);
        acc1 = __builtin_amdgcn_mfma_f32_16x16x32_bf16(Ah1, Bh[1][1], acc1, 0, 0, 0);

        // xor8 exchange via DPP (VALU): complete (i,f,g,o) for my 2 C rows
        float e0 = dpp_xor8(lohalf ? acc0[2] : acc0[0]);
        float e1 = dpp_xor8(lohalf ? acc0[3] : acc0[1]);
        float e2 = dpp_xor8(lohalf ? acc1[2] : acc1[0]);
        float e3 = dpp_xor8(lohalf ? acc1[3] : acc1[1]);

        float i0 = lohalf ? acc0[0] : e0;    // row r0
        float f0 = lohalf ? e0 : acc0[2];
        float g0 = lohalf ? acc1[0] : e2;
        float o0 = lohalf ? e2 : acc1[2];
        float i1 = lohalf ? acc0[1] : e1;    // row r0+1
        float f1 = lohalf ? e1 : acc0[3];
        float g1 = lohalf ? acc1[1] : e3;
        float o1 = lohalf ? e3 : acc1[3];

        // xor32: ship row-B gates; lanes>=32 take over partner's row r0+1
        float ri = __shfl_xor(i1, 32);
        float rf = __shfl_xor(f1, 32);
        float rg = __shfl_xor(g1, 32);
        float ro = __shfl_xor(o1, 32);
        float gi = hiw ? ri : i0;
        float gf = hiw ? rf : f0;
        float gg = hiw ? rg : g0;
        float go = hiw ? ro : o0;

        cc   = sigmoid_f(gf) * cc + sigmoid_f(gi) * tanh_f(gg);
        hcur = sigmoid_f(go) * tanh_f(cc);

        wh[woff] = f2bf_rne(hcur);
    };

    for (int it = 0; it < T_STEPS / 2; ++it) {
        step(hbuf[0], hbuf[1], I0, I1, J0, J1, 2 * it);
        barrier_lgkm();
        step(hbuf[1], hbuf[0], J0, J1, I0, I1, 2 * it + 1);
        barrier_lgkm();
    }

    // every thread owns exactly one (b, j)
    {
        int j = wave * 8 + (m & 7);
        hfin[(dir * BATCH + b_base + row) * HH + j] = hcur;
    }
}

// ---------------- Kernel 3: final FC (W_fc in LDS, 8 rows/block) ----------
__global__ __launch_bounds__(256) void fc_kernel(
    const float* __restrict__ hfin,    // [2][1024][64]
    const float* __restrict__ W_fc,    // [128][128]
    const float* __restrict__ b_fc,    // [128]
    float* __restrict__ out)           // [1024][128]
{
    __shared__ float wfc[HID * 129];   // row-padded: bank stride 129
    __shared__ float hid[8][HID];
    const int tid = threadIdx.x;
    const int b0  = blockIdx.x * 8;

    for (int i = tid; i < HID * HID; i += 256) {
        int r = i >> 7, c = i & 127;
        wfc[r * 129 + c] = W_fc[i];
    }
    for (int i = tid; i < 8 * HID; i += 256) {
        int bb = i >> 7, v = i & 127;
        hid[bb][v] = (v < HH) ? hfin[(0 * BATCH + b0 + bb) * HH + v]
                              : hfin[(1 * BATCH + b0 + bb) * HH + (v - HH)];
    }
    __syncthreads();

    const int v  = tid & 127;
    const int bs = (tid >> 7) * 4;     // rows [bs, bs+4)
    const float bias = b_fc[v];
    const float* wrow = wfc + v * 129;
#pragma unroll
    for (int r = 0; r < 4; ++r) {
        const float* h = hid[bs + r];
        float acc = bias;
#pragma unroll
        for (int k = 0; k < HID; k += 4) {
            acc += wrow[k]     * h[k]     + wrow[k + 1] * h[k + 1]
                 + wrow[k + 2] * h[k + 2] + wrow[k + 3] * h[k + 3];
        }
        out[(b0 + bs + r) * HID + v] = acc;
    }
}

extern "C" void kernel_launch(void* const* d_in, const int* in_sizes, int n_in,
                              void* d_out, int out_size, void* d_ws, size_t ws_size,
                              hipStream_t stream) {
    const int*   x      = (const int*)d_in[0];
    // d_in[1] = lengths : unused by the reference
    const float* emb    = (const float*)d_in[2];
    const float* W_ih_f = (const float*)d_in[3];
    const float* W_hh_f = (const float*)d_in[4];
    const float* W_ih_b = (const float*)d_in[5];
    const float* W_hh_b = (const float*)d_in[6];
    const float* W_fc   = (const float*)d_in[7];
    const float* b_fc   = (const float*)d_in[8];
    float* out = (float*)d_out;

    float* tab2   = (float*)d_ws;                         // 65536 f32 (pairs)
    u16*   whh_bf = (u16*)(tab2 + 2 * VOCAB * NG);        // 32768 u16
    float* hfin   = (float*)(whh_bf + 2 * NG * HH);       // 131072 f32

    build_tab_kernel<<<dim3(VOCAB, 2), 256, 0, stream>>>(
        emb, W_ih_f, W_ih_b, W_hh_f, W_hh_b, tab2, whh_bf);
    lstm_rec_kernel<<<dim3(BATCH / MB, 2), 512, 0, stream>>>(x, whh_bf, tab2, hfin);
    fc_kernel<<<dim3(BATCH / 8), 256, 0, stream>>>(hfin, W_fc, b_fc, out);
}

// Round 16
// 303.530 us; speedup vs baseline: 1.3093x; 1.0556x over previous
//
#include <hip/hip_runtime.h>
#include <hip/hip_bf16.h>

// BLSTM: B=1024, T=512, V=128, H=128, HH=64, gates=256/dir.
// R16: R15 + ONE change — duplicated M-rows kill the xor32 exchange.
// h is written to M-rows r AND r+8 (extra ds_write_b16, off the critical
// path); MFMA then computes C rows 8..15 as bit-exact duplicates of rows
// 0..7, so lanes>=32 (quads 2,3) natively hold the complete real gate set
// that the 4 ds_bpermute (~120cyc, in-chain) used to ship them. Selection
// becomes a local cndmask on (quad>>1). absmax must stay EXACTLY 9.766e-4
// (bit-identical math) — that's the correctness oracle.
// Rec skeleton (R9-R15): MB=8, 8 waves, 1 lgkm-barrier/step, pure-bf16 gate
// GEMM (4 MFMAs), conflict-free A-frag h layout, DPP xor8, rcp/exp2
// transcendentals, one sigma-chain per lane.

#define T_STEPS 512
#define BATCH   1024
#define VOCAB   128
#define HID     128
#define HH      64
#define NG      256
#define MB      8      // real batch rows per block

#define L2E  1.4426950408889634f
#define L2E2 2.8853900817779268f

typedef __attribute__((ext_vector_type(8))) short bf16x8;
typedef __attribute__((ext_vector_type(4))) float f32x4;
typedef unsigned int  u32;
typedef unsigned short u16;

__device__ __forceinline__ float sigmoid_f(float x) {
    return __builtin_amdgcn_rcpf(1.0f + __builtin_amdgcn_exp2f(-x * L2E));
}
__device__ __forceinline__ float tanh_f(float x) {
    return 1.0f - 2.0f * __builtin_amdgcn_rcpf(1.0f + __builtin_amdgcn_exp2f(x * L2E2));
}
__device__ __forceinline__ u16 f2bf_rne(float f) {
    u32 u = __builtin_bit_cast(u32, f);
    u += 0x7FFFu + ((u >> 16) & 1u);
    return (u16)(u >> 16);
}
// lane^8 within each 16-lane row == DPP row_ror:8 (VALU, no DS round trip)
__device__ __forceinline__ float dpp_xor8(float v) {
    int i = __builtin_bit_cast(int, v);
    i = __builtin_amdgcn_mov_dpp(i, 0x128, 0xF, 0xF, true);
    return __builtin_bit_cast(float, i);
}
// barrier with LDS-only drain: h produce/consume needs lgkmcnt(0)+s_barrier;
// global (tab) loads are NOT drained — their waitcnt lands at the use point.
__device__ __forceinline__ void barrier_lgkm() {
    asm volatile("s_waitcnt lgkmcnt(0)\n\ts_barrier" ::: "memory");
}

// permuted gate column c (0..255) -> original gate row g
__device__ __forceinline__ int perm_gate(int c) {
    int tile = c >> 7, rest = c & 127, w = rest >> 4, m = rest & 15;
    return (m < 8) ? (tile * 128 + w * 8 + m)
                   : (tile * 128 + 64 + w * 8 + (m - 8));
}

// ---------------- Kernel 1: tab build + W_hh bf16 convert (fused) ----------
__global__ __launch_bounds__(256) void build_tab_kernel(
    const float* __restrict__ emb,
    const float* __restrict__ W_ih_f,
    const float* __restrict__ W_ih_b,
    const float* __restrict__ W_hh_f,
    const float* __restrict__ W_hh_b,
    float* __restrict__ tab2,
    u16*   __restrict__ whh_bf)
{
    int v = blockIdx.x, d = blockIdx.y, gp = threadIdx.x;
    int tile = gp >> 7, c0 = gp & 127;
    int g = perm_gate(tile * 128 + c0);
    const float* W = d ? W_ih_b : W_ih_f;
    const float4* e4 = (const float4*)(emb + v * HID);
    const float4* w4 = (const float4*)(W + g * HID);
    float acc = 0.0f;
#pragma unroll
    for (int k = 0; k < HID / 4; ++k) {
        float4 e = e4[k]; float4 w = w4[k];
        acc += e.x * w.x + e.y * w.y + e.z * w.z + e.w * w.w;
    }
    tab2[((d * VOCAB + v) * 128 + c0) * 2 + tile] = acc;

    // fused W_hh convert: (d, v) block covers elems [(d*128+v)*128, +128)
    if (gp < 128) {
        const float* Whh = d ? W_hh_b : W_hh_f;
        int idx = v * 128 + gp;           // 0..16383 within this dir
        whh_bf[d * NG * HH + idx] = f2bf_rne(Whh[idx]);
    }
}

// ---------------- Kernel 2: MFMA recurrence ----------------
// grid (128,2), block 512 (8 waves), 1 block/CU.
__global__ __launch_bounds__(512, 2) void lstm_rec_kernel(
    const int*  __restrict__ x,        // [1024][512]
    const u16*  __restrict__ whh_bf,   // [2][256][64] bf16 bits (orig order)
    const float* __restrict__ tab2,    // [2][128][128] float2 pairs, permuted
    float* __restrict__ hfin)          // [2][1024][64]
{
    __shared__ u32 xs2[T_STEPS][MB];     // v*128 (pair index), 16 KB
    __shared__ u16 hbuf[2][1024];        // [pingpong][elem], 4 KB

    const int tid  = threadIdx.x;
    const int lane = tid & 63;
    const int wave = tid >> 6;           // 0..7
    const int quad = lane >> 4;          // 0..3
    const int m    = lane & 15;
    const int dir    = blockIdx.y;
    const int b_base = blockIdx.x * MB;

    // stage x, pre-scaled to tab2 pair index (v*128)
    for (int i = tid; i < MB * T_STEPS; i += 512) {
        int bl = i >> 9, t = i & (T_STEPS - 1);
        xs2[t][bl] = ((u32)x[(b_base + bl) * T_STEPS + t]) << 7;
    }
    // zero both h buffers (M-rows 8..15 = duplicates, also zeroed)
    for (int i = tid; i < 1024; i += 512) ((u32*)hbuf)[i] = 0;

    // persistent B-fragments, permuted gate rows
    const u16* WB = whh_bf + dir * NG * HH;
    bf16x8 Bh[2][2];
#pragma unroll
    for (int tile = 0; tile < 2; ++tile) {
        int grow = perm_gate(tile * 128 + wave * 16 + m);
#pragma unroll
        for (int kc = 0; kc < 2; ++kc)
            Bh[tile][kc] = *(const bf16x8*)(WB + grow * HH + kc * 32 + quad * 8);
    }

    const float2* tabD = (const float2*)tab2 + dir * VOCAB * 128;
    const int  c0      = wave * 16 + m;          // pair-column 0..127
    const bool lohalf  = (m < 8);
    const bool second  = (quad >= 2);            // take row r0+1's gate set
    // the ONE real row this lane finalizes in phase B:
    const int  row     = 4 * (quad & 1) + (lohalf ? 0 : 2) + (quad >> 1);
    const int  wbase   = (wave >> 2) * 512 + (wave & 3) * 128 + (m & 7);
    const int  woff    = wbase + row * 8;        // M-row `row`
    const int  woff2   = woff + 64;              // duplicate at M-row row+8
    const int  aoff    = lane * 8;               // u16 units
    const int  xrow    = (quad & 1) * 4;         // xs2 sub-row for my 4 C-rows

    float cc = 0.f, hcur = 0.f;
    float I0[4], I1[4], J0[4], J1[4];

    __syncthreads();   // xs2 + hbuf init visible (full barrier once, fine)

    {   // prefetch step 0
        int t0 = dir ? (T_STEPS - 1) : 0;
        int4 vv = *(const int4*)&xs2[t0][xrow];
        float2 p0 = tabD[(u32)vv.x + c0];
        float2 p1 = tabD[(u32)vv.y + c0];
        float2 p2 = tabD[(u32)vv.z + c0];
        float2 p3 = tabD[(u32)vv.w + c0];
        I0[0] = p0.x; I1[0] = p0.y;
        I0[1] = p1.x; I1[1] = p1.y;
        I0[2] = p2.x; I1[2] = p2.y;
        I0[3] = p3.x; I1[3] = p3.y;
    }

    auto step = [&](const u16* rh, u16* wh,
                    float (&cur0)[4], float (&cur1)[4],
                    float (&nx0)[4], float (&nx1)[4], int s) {
        bf16x8 Ah0 = *(const bf16x8*)(rh + aoff);
        bf16x8 Ah1 = *(const bf16x8*)(rh + 512 + aoff);

        // prefetch next step's tab init (global; vmcnt wait lands at use,
        // NOT at the barrier — barrier_lgkm drains LDS only)
        {
            int sn = (s + 1 < T_STEPS) ? s + 1 : s;
            int tn = dir ? (T_STEPS - 1 - sn) : sn;
            int4 vv = *(const int4*)&xs2[tn][xrow];   // one ds_read_b128
            float2 p0 = tabD[(u32)vv.x + c0];
            float2 p1 = tabD[(u32)vv.y + c0];
            float2 p2 = tabD[(u32)vv.z + c0];
            float2 p3 = tabD[(u32)vv.w + c0];
            nx0[0] = p0.x; nx1[0] = p0.y;
            nx0[1] = p1.x; nx1[1] = p1.y;
            nx0[2] = p2.x; nx1[2] = p2.y;
            nx0[3] = p3.x; nx1[3] = p3.y;
        }

        // pure-bf16 gate GEMM: 4 MFMAs, dependent depth 2.
        // A rows 8..15 duplicate rows 0..7 -> C rows 8..15 are bit-exact
        // duplicates: quads 2,3 natively hold real gate values.
        f32x4 acc0 = {cur0[0], cur0[1], cur0[2], cur0[3]};
        f32x4 acc1 = {cur1[0], cur1[1], cur1[2], cur1[3]};
        acc0 = __builtin_amdgcn_mfma_f32_16x16x32_bf16(Ah0, Bh[0][0], acc0, 0, 0, 0);
        acc1 = __builtin_amdgcn_mfma_f32_16x16x32_bf16(Ah0, Bh[1][0], acc1, 0, 0, 0);
        acc0 = __builtin_amdgcn_mfma_f32_16x16x32_bf16(Ah1, Bh[0][1], acc0, 0, 0, 0);
        acc1 = __builtin_amdgcn_mfma_f32_16x16x32_bf16(Ah1, Bh[1][1], acc1, 0, 0, 0);

        // xor8 exchange via DPP (VALU): complete (i,f,g,o) for my 2 C rows
        float e0 = dpp_xor8(lohalf ? acc0[2] : acc0[0]);
        float e1 = dpp_xor8(lohalf ? acc0[3] : acc0[1]);
        float e2 = dpp_xor8(lohalf ? acc1[2] : acc1[0]);
        float e3 = dpp_xor8(lohalf ? acc1[3] : acc1[1]);

        float i0 = lohalf ? acc0[0] : e0;    // row r0
        float f0 = lohalf ? e0 : acc0[2];
        float g0 = lohalf ? acc1[0] : e2;
        float o0 = lohalf ? e2 : acc1[2];
        float i1 = lohalf ? acc0[1] : e1;    // row r0+1
        float f1 = lohalf ? e1 : acc0[3];
        float g1 = lohalf ? acc1[1] : e3;
        float o1 = lohalf ? e3 : acc1[3];

        // row select (was xor32 bpermute): quads 2,3 keep their own
        // duplicated row r0+1 values — pure local cndmask, no lane traffic
        float gi = second ? i1 : i0;
        float gf = second ? f1 : f0;
        float gg = second ? g1 : g0;
        float go = second ? o1 : o0;

        cc   = sigmoid_f(gf) * cc + sigmoid_f(gi) * tanh_f(gg);
        hcur = sigmoid_f(go) * tanh_f(cc);

        u16 hb = f2bf_rne(hcur);
        wh[woff]  = hb;        // M-row `row`
        wh[woff2] = hb;        // duplicate at M-row row+8
    };

    for (int it = 0; it < T_STEPS / 2; ++it) {
        step(hbuf[0], hbuf[1], I0, I1, J0, J1, 2 * it);
        barrier_lgkm();
        step(hbuf[1], hbuf[0], J0, J1, I0, I1, 2 * it + 1);
        barrier_lgkm();
    }

    // every thread owns exactly one (b, j)
    {
        int j = wave * 8 + (m & 7);
        hfin[(dir * BATCH + b_base + row) * HH + j] = hcur;
    }
}

// ---------------- Kernel 3: final FC (W_fc in LDS, 8 rows/block) ----------
__global__ __launch_bounds__(256) void fc_kernel(
    const float* __restrict__ hfin,    // [2][1024][64]
    const float* __restrict__ W_fc,    // [128][128]
    const float* __restrict__ b_fc,    // [128]
    float* __restrict__ out)           // [1024][128]
{
    __shared__ float wfc[HID * 129];   // row-padded: bank stride 129
    __shared__ float hid[8][HID];
    const int tid = threadIdx.x;
    const int b0  = blockIdx.x * 8;

    for (int i = tid; i < HID * HID; i += 256) {
        int r = i >> 7, c = i & 127;
        wfc[r * 129 + c] = W_fc[i];
    }
    for (int i = tid; i < 8 * HID; i += 256) {
        int bb = i >> 7, v = i & 127;
        hid[bb][v] = (v < HH) ? hfin[(0 * BATCH + b0 + bb) * HH + v]
                              : hfin[(1 * BATCH + b0 + bb) * HH + (v - HH)];
    }
    __syncthreads();

    const int v  = tid & 127;
    const int bs = (tid >> 7) * 4;     // rows [bs, bs+4)
    const float bias = b_fc[v];
    const float* wrow = wfc + v * 129;
#pragma unroll
    for (int r = 0; r < 4; ++r) {
        const float* h = hid[bs + r];
        float acc = bias;
#pragma unroll
        for (int k = 0; k < HID; k += 4) {
            acc += wrow[k]     * h[k]     + wrow[k + 1] * h[k + 1]
                 + wrow[k + 2] * h[k + 2] + wrow[k + 3] * h[k + 3];
        }
        out[(b0 + bs + r) * HID + v] = acc;
    }
}

extern "C" void kernel_launch(void* const* d_in, const int* in_sizes, int n_in,
                              void* d_out, int out_size, void* d_ws, size_t ws_size,
                              hipStream_t stream) {
    const int*   x      = (const int*)d_in[0];
    // d_in[1] = lengths : unused by the reference
    const float* emb    = (const float*)d_in[2];
    const float* W_ih_f = (const float*)d_in[3];
    const float* W_hh_f = (const float*)d_in[4];
    const float* W_ih_b = (const float*)d_in[5];
    const float* W_hh_b = (const float*)d_in[6];
    const float* W_fc   = (const float*)d_in[7];
    const float* b_fc   = (const float*)d_in[8];
    float* out = (float*)d_out;

    float* tab2   = (float*)d_ws;                         // 65536 f32 (pairs)
    u16*   whh_bf = (u16*)(tab2 + 2 * VOCAB * NG);        // 32768 u16
    float* hfin   = (float*)(whh_bf + 2 * NG * HH);       // 131072 f32

    build_tab_kernel<<<dim3(VOCAB, 2), 256, 0, stream>>>(
        emb, W_ih_f, W_ih_b, W_hh_f, W_hh_b, tab2, whh_bf);
    lstm_rec_kernel<<<dim3(BATCH / MB, 2), 512, 0, stream>>>(x, whh_bf, tab2, hfin);
    fc_kernel<<<dim3(BATCH / 8), 256, 0, stream>>>(hfin, W_fc, b_fc, out);
}